// Round 16
// baseline (320.707 us; speedup 1.0000x reference)
//
#include <hip/hip_runtime.h>

constexpr int BLK = 256;
constexpr int NBLKBIN = 512;      // blocks for binning passes
constexpr int MAXNB   = 1024;     // max buckets (128 dst each -> n <= 131072)

typedef __bf16 bf16x8 __attribute__((ext_vector_type(8)));
typedef float  f32x4  __attribute__((ext_vector_type(4)));

__device__ __forceinline__ float blo(unsigned u) { return __uint_as_float(u << 16); }
__device__ __forceinline__ float bhi(unsigned u) { return __uint_as_float(u & 0xffff0000u); }

__device__ __forceinline__ int detect64(const void* ei) {
    const int* p = (const int*)ei;
    int is64 = 1;
#pragma unroll
    for (int i = 0; i < 16; ++i)
        if (p[2 * i + 1] != 0) is64 = 0;
    return is64;
}

__device__ __forceinline__ int load_idx(const void* ei, size_t pos, int is64) {
    if (is64) return (int)((const long long*)ei)[pos];
    return ((const int*)ei)[pos];
}

// ---------------------------------------------------------------- prep: weights -> frag bf16, zero bkt_cnt
__global__ void k_prep(const float* __restrict__ W1, const float* __restrict__ W2,
                       __bf16* __restrict__ Wtf, __bf16* __restrict__ Wtf2,
                       int* __restrict__ bkt_cnt, int nb) {
    const int b = blockIdx.x;
    const int t = threadIdx.x;
    if (b < 16) {                         // W1 [512][64] -> Wtf (4096 frags of 8)
        int i = b * 256 + t;
        int lane = i & 63;
        int tt   = (i >> 6) & 3;
        int k0c  = i >> 8;
        int col  = tt * 16 + (lane & 15);
        int kbase = k0c * 32 + (lane >> 4) * 8;
        bf16x8 v;
#pragma unroll
        for (int j = 0; j < 8; ++j) v[j] = (__bf16)W1[(size_t)(kbase + j) * 64 + col];
        *(bf16x8*)(Wtf + (size_t)i * 8) = v;
    } else if (b == 16) {                 // W2 [64][32] -> Wtf2 (256 frags of 8)
        int i = t;
        int lane = i & 63;
        int ct   = i >> 6;
        int tt = ct & 1, chunk = ct >> 1;
        int col  = tt * 16 + (lane & 15);
        int kbase = chunk * 32 + (lane >> 4) * 8;
        bf16x8 v;
#pragma unroll
        for (int j = 0; j < 8; ++j) v[j] = (__bf16)W2[(size_t)(kbase + j) * 32 + col];
        *(bf16x8*)(Wtf2 + (size_t)i * 8) = v;
    } else {                              // zero bucket counters
        for (int i = t; i < nb; i += 256) bkt_cnt[i] = 0;
    }
}

// ---------------------------------------------------------------- B1: bucket histogram; persist per-block bases
__global__ __launch_bounds__(256) void k_binhist(const void* __restrict__ ei, int e,
                                                 int* __restrict__ bucket_cnt,
                                                 int* __restrict__ blkbase, int nb) {
    __shared__ int hist[MAXNB];
    const int t = threadIdx.x;
    for (int b = t; b < nb; b += 256) hist[b] = 0;
    __syncthreads();
    const int is64 = detect64(ei);
    const int chunk = (e + NBLKBIN - 1) / NBLKBIN;
    const int i0 = blockIdx.x * chunk;
    const int i1 = min(e, i0 + chunk);
    for (int i = i0 + t; i < i1; i += 256) {
        int dst = load_idx(ei, (size_t)e + i, is64);
        atomicAdd(&hist[dst >> 7], 1);
    }
    __syncthreads();
    int* myb = blkbase + (size_t)blockIdx.x * MAXNB;
    for (int b = t; b < nb; b += 256) {
        int c = hist[b];
        int base = 0;
        if (c) base = atomicAdd(&bucket_cnt[b], c);
        myb[b] = base;
    }
}

// helper: block-wide prefix over bkt_cnt -> pfx[MAXNB] (inclusive)
__device__ __forceinline__ void bucket_prefix(const int* __restrict__ bkt_cnt, int nb,
                                              int* scn, int* pfx) {
    const int t = threadIdx.x;
    const int base = t * 4;
    int v[4]; int s = 0;
#pragma unroll
    for (int k = 0; k < 4; ++k) {
        int i = base + k;
        v[k] = (i < nb) ? bkt_cnt[i] : 0;
        s += v[k];
    }
    scn[t] = s;
    __syncthreads();
    for (int d = 1; d < 256; d <<= 1) {
        int x = (t >= d) ? scn[t - d] : 0;
        __syncthreads();
        scn[t] += x;
        __syncthreads();
    }
    int run = (t == 0) ? 0 : scn[t - 1];
#pragma unroll
    for (int k = 0; k < 4; ++k) {
        run += v[k];
        pfx[base + k] = run;            // inclusive
    }
    __syncthreads();
}

// ---------------------------------------------------------------- B3: SINGLE-PASS scatter
__global__ __launch_bounds__(256) void k_binscatter(const void* __restrict__ ei,
                                                    const float* __restrict__ ew, int e,
                                                    const int* __restrict__ bkt_cnt,
                                                    const int* __restrict__ blkbase,
                                                    int2* __restrict__ binned, int nb) {
    __shared__ int scn[256];
    __shared__ int hist[MAXNB];
    const int t = threadIdx.x;
    const int base = t * 4;
    int v[4]; int s = 0;
#pragma unroll
    for (int k = 0; k < 4; ++k) {
        int i = base + k;
        v[k] = (i < nb) ? bkt_cnt[i] : 0;
        s += v[k];
    }
    scn[t] = s;
    __syncthreads();
    for (int d = 1; d < 256; d <<= 1) {
        int x = (t >= d) ? scn[t - d] : 0;
        __syncthreads();
        scn[t] += x;
        __syncthreads();
    }
    int excl = (t == 0) ? 0 : scn[t - 1];
    const int* myb = blkbase + (size_t)blockIdx.x * MAXNB;
#pragma unroll
    for (int k = 0; k < 4; ++k) {
        int i = base + k;
        if (i < nb) hist[i] = excl + myb[i];
        excl += v[k];
    }
    __syncthreads();
    const int is64 = detect64(ei);
    const int chunk = (e + NBLKBIN - 1) / NBLKBIN;
    const int i0 = blockIdx.x * chunk;
    const int i1 = min(e, i0 + chunk);
    for (int i = i0 + t; i < i1; i += 256) {
        int dst = load_idx(ei, (size_t)e + i, is64);
        int src = load_idx(ei, (size_t)i, is64);
        float w = ew[i];
        int bin = dst >> 7;
        int pos = atomicAdd(&hist[bin], 1);
        binned[pos] = make_int2(src | ((dst & 127) << 20), __float_as_int(w));
    }
}

// ---------------------------------------------------------------- B4: fused build
__global__ __launch_bounds__(256) void k_build(const int* __restrict__ bkt_cnt,
                                               const int2* __restrict__ binned,
                                               float* __restrict__ dinv,
                                               int* __restrict__ offs,
                                               int2* __restrict__ csrp, int n, int e, int nb) {
    __shared__ int                scn[256];
    __shared__ int                pfx[MAXNB];
    __shared__ int                icnt[128];
    __shared__ unsigned long long facc[128];
    __shared__ int                scn2[128];
    __shared__ int                cur[128];
    const int t = threadIdx.x;
    const int b = blockIdx.x;
    bucket_prefix(bkt_cnt, nb, scn, pfx);
    const int j0 = (b == 0) ? 0 : pfx[b - 1];
    const int j1 = pfx[b];
    if (t < 128) { icnt[t] = 0; facc[t] = 0ull; }
    __syncthreads();
    const float SCALE = 1099511627776.f;      // 2^40
    for (int j = j0 + t; j < j1; j += 256) {
        int2 p = binned[j];
        int dl = ((unsigned)p.x) >> 20;
        atomicAdd(&icnt[dl], 1);
        atomicAdd(&facc[dl], (unsigned long long)(__int_as_float(p.y) * SCALE));
    }
    __syncthreads();
    if (t < 128) {
        int nd = b * 128 + t;
        if (nd < n) dinv[nd] = rsqrtf(fmaf((float)facc[t], 1.f / 1099511627776.f, 1.0f));
        scn2[t] = icnt[t];
    }
    __syncthreads();
    for (int d = 1; d < 128; d <<= 1) {
        int x = 0;
        if (t < 128 && t >= d) x = scn2[t - d];
        __syncthreads();
        if (t < 128) scn2[t] += x;
        __syncthreads();
    }
    if (t < 128) {
        int excl = (t == 0) ? 0 : scn2[t - 1];
        int abs0 = j0 + excl;
        cur[t] = abs0;
        int nd = b * 128 + t;
        if (nd < n) offs[nd] = abs0;
    }
    if (b == 0 && t == 0) offs[n] = e;
    __syncthreads();
    for (int j = j0 + t; j < j1; j += 256) {
        int2 p = binned[j];
        int dl  = ((unsigned)p.x) >> 20;
        int src = p.x & 0xFFFFF;
        int pos = atomicAdd(&cur[dl], 1);
        csrp[pos] = make_int2(src, p.y);      // raw weight; dinv folded into h'
    }
}

// ---------------------------------------------------------------- GEMM1: bf16 MFMA, 64 rows/wave, h' = dinv*h
__global__ __launch_bounds__(256) void k_gemm1_mfma(const float* __restrict__ X,
                                                    const __bf16* __restrict__ Wtf,
                                                    const float* __restrict__ dinv,
                                                    __bf16* __restrict__ H, int nrows) {
    const int wave = threadIdx.x >> 6;
    const int lane = threadIdx.x & 63;
    const int l15  = lane & 15;
    const int lq   = lane >> 4;
    const long rbase = (long)blockIdx.x * 256 + wave * 64;

    const float4* xr[4];
#pragma unroll
    for (int rg = 0; rg < 4; ++rg) {
        long ar = rbase + rg * 16 + l15;
        if (ar >= nrows) ar = nrows - 1;
        xr[rg] = (const float4*)(X + (size_t)ar * 512) + lq * 2;
    }

    f32x4 acc[4][4];
#pragma unroll
    for (int rg = 0; rg < 4; ++rg)
#pragma unroll
        for (int tt = 0; tt < 4; ++tt) acc[rg][tt] = f32x4{0.f, 0.f, 0.f, 0.f};

    float4 pa[2][4][2];   // [stage][rowgroup][half] - all static indices
#pragma unroll
    for (int s = 0; s < 2; ++s)
#pragma unroll
        for (int rg = 0; rg < 4; ++rg) {
            pa[s][rg][0] = xr[rg][s * 8];
            pa[s][rg][1] = xr[rg][s * 8 + 1];
        }

#pragma unroll
    for (int k0c = 0; k0c < 16; ++k0c) {
        const int s = k0c & 1;
        bf16x8 af[4];
#pragma unroll
        for (int rg = 0; rg < 4; ++rg) {
            float4 a0 = pa[s][rg][0], a1 = pa[s][rg][1];
            af[rg][0] = (__bf16)a0.x; af[rg][1] = (__bf16)a0.y;
            af[rg][2] = (__bf16)a0.z; af[rg][3] = (__bf16)a0.w;
            af[rg][4] = (__bf16)a1.x; af[rg][5] = (__bf16)a1.y;
            af[rg][6] = (__bf16)a1.z; af[rg][7] = (__bf16)a1.w;
        }
        if (k0c + 2 < 16) {
#pragma unroll
            for (int rg = 0; rg < 4; ++rg) {
                pa[s][rg][0] = xr[rg][(k0c + 2) * 8];
                pa[s][rg][1] = xr[rg][(k0c + 2) * 8 + 1];
            }
        }
#pragma unroll
        for (int tt = 0; tt < 4; ++tt) {
            bf16x8 bf_ = *(const bf16x8*)(Wtf + ((size_t)(k0c * 4 + tt) * 64 + lane) * 8);
#pragma unroll
            for (int rg = 0; rg < 4; ++rg)
                acc[rg][tt] = __builtin_amdgcn_mfma_f32_16x16x32_bf16(af[rg], bf_, acc[rg][tt], 0, 0, 0);
        }
    }
#pragma unroll
    for (int rg = 0; rg < 4; ++rg)
#pragma unroll
    for (int r = 0; r < 4; ++r) {
        long row = rbase + rg * 16 + lq * 4 + r;
        if (row < nrows) {
            float dv = dinv[row];
#pragma unroll
            for (int tt = 0; tt < 4; ++tt)
                H[(size_t)row * 64 + tt * 16 + l15] = (__bf16)(acc[rg][tt][r] * dv);
        }
    }
}

// ---------------------------------------------------------------- GEMM2: 64 -> 32 bf16 MFMA, h' = dinv*h
__global__ __launch_bounds__(256) void k_gemm2_mfma(const __bf16* __restrict__ A,
                                                    const __bf16* __restrict__ Wtf2,
                                                    const float* __restrict__ dinv,
                                                    __bf16* __restrict__ H, int nrows) {
    const int wave = threadIdx.x >> 6;
    const int lane = threadIdx.x & 63;
    const int l15  = lane & 15;
    const int lq   = lane >> 4;
    const long rbase = (long)blockIdx.x * 64 + wave * 16;

    long arow = rbase + l15;
    if (arow >= nrows) arow = nrows - 1;

    f32x4 acc[2] = {{0.f,0.f,0.f,0.f},{0.f,0.f,0.f,0.f}};
#pragma unroll
    for (int c = 0; c < 2; ++c) {
        bf16x8 af = *(const bf16x8*)(A + (size_t)arow * 64 + c * 32 + lq * 8);
#pragma unroll
        for (int t = 0; t < 2; ++t) {
            bf16x8 bf_ = *(const bf16x8*)(Wtf2 + ((size_t)(c * 2 + t) * 64 + lane) * 8);
            acc[t] = __builtin_amdgcn_mfma_f32_16x16x32_bf16(af, bf_, acc[t], 0, 0, 0);
        }
    }
#pragma unroll
    for (int r = 0; r < 4; ++r) {
        long row = rbase + lq * 4 + r;
        if (row < nrows) {
            float dv = dinv[row];
#pragma unroll
            for (int t = 0; t < 2; ++t)
                H[(size_t)row * 32 + t * 16 + l15] = (__bf16)(acc[t][r] * dv);
        }
    }
}

// ---------------------------------------------------------------- propagation (CSR gather, bf16 h', 16B/lane)
// h' = dinv*h; out = di*(sum w*h'[src] + h'[nd]) + b ; lane owns 8 channels (16B load)
// EPI 0: relu -> packed bf16    EPI 1: fused lin3 -> h3' = dinv * (relu(o)·W3)
template <int K, int EPI>
__global__ __launch_bounds__(256) void k_prop_bf(const int* __restrict__ offs,
                                                 const int2* __restrict__ csrp,
                                                 const __bf16* __restrict__ hb,
                                                 const float* __restrict__ dinv,
                                                 const float* __restrict__ bias,
                                                 const float* __restrict__ W3,
                                                 void* __restrict__ outv, int n) {
    constexpr int SUB = K / 8;           // lanes per node (8 for K=64, 4 for K=32)
    constexpr int NPW = 64 / SUB;        // nodes per wave
    constexpr int NPB = 4 * NPW;         // nodes per block
    const int t    = threadIdx.x;
    const int lane = t & 63;
    const int wave = t >> 6;
    const int cho  = lane & (SUB - 1);   // channel-octet index
    const int sub  = lane / SUB;
    const long nd  = (long)blockIdx.x * NPB + wave * NPW + sub;
    if (nd >= n) return;

    const unsigned short* h = (const unsigned short*)hb;
    const int j0 = offs[nd], j1 = offs[nd + 1];
    float a0 = 0.f, a1 = 0.f, a2 = 0.f, a3 = 0.f;
    float a4 = 0.f, a5 = 0.f, a6 = 0.f, a7 = 0.f;
    int j = j0;
    for (; j + 3 < j1; j += 4) {
        int2 p0 = csrp[j];
        int2 p1 = csrp[j + 1];
        int2 p2 = csrp[j + 2];
        int2 p3 = csrp[j + 3];
        uint4 u0 = *(const uint4*)(h + (size_t)p0.x * K + 8 * cho);
        uint4 u1 = *(const uint4*)(h + (size_t)p1.x * K + 8 * cho);
        uint4 u2 = *(const uint4*)(h + (size_t)p2.x * K + 8 * cho);
        uint4 u3 = *(const uint4*)(h + (size_t)p3.x * K + 8 * cho);
        float w0 = __int_as_float(p0.y), w1 = __int_as_float(p1.y);
        float w2 = __int_as_float(p2.y), w3 = __int_as_float(p3.y);
        a0 = fmaf(w0, blo(u0.x), a0); a1 = fmaf(w0, bhi(u0.x), a1);
        a2 = fmaf(w0, blo(u0.y), a2); a3 = fmaf(w0, bhi(u0.y), a3);
        a4 = fmaf(w0, blo(u0.z), a4); a5 = fmaf(w0, bhi(u0.z), a5);
        a6 = fmaf(w0, blo(u0.w), a6); a7 = fmaf(w0, bhi(u0.w), a7);
        a0 = fmaf(w1, blo(u1.x), a0); a1 = fmaf(w1, bhi(u1.x), a1);
        a2 = fmaf(w1, blo(u1.y), a2); a3 = fmaf(w1, bhi(u1.y), a3);
        a4 = fmaf(w1, blo(u1.z), a4); a5 = fmaf(w1, bhi(u1.z), a5);
        a6 = fmaf(w1, blo(u1.w), a6); a7 = fmaf(w1, bhi(u1.w), a7);
        a0 = fmaf(w2, blo(u2.x), a0); a1 = fmaf(w2, bhi(u2.x), a1);
        a2 = fmaf(w2, blo(u2.y), a2); a3 = fmaf(w2, bhi(u2.y), a3);
        a4 = fmaf(w2, blo(u2.z), a4); a5 = fmaf(w2, bhi(u2.z), a5);
        a6 = fmaf(w2, blo(u2.w), a6); a7 = fmaf(w2, bhi(u2.w), a7);
        a0 = fmaf(w3, blo(u3.x), a0); a1 = fmaf(w3, bhi(u3.x), a1);
        a2 = fmaf(w3, blo(u3.y), a2); a3 = fmaf(w3, bhi(u3.y), a3);
        a4 = fmaf(w3, blo(u3.z), a4); a5 = fmaf(w3, bhi(u3.z), a5);
        a6 = fmaf(w3, blo(u3.w), a6); a7 = fmaf(w3, bhi(u3.w), a7);
    }
    for (; j < j1; ++j) {
        int2 p0 = csrp[j];
        uint4 u0 = *(const uint4*)(h + (size_t)p0.x * K + 8 * cho);
        float w0 = __int_as_float(p0.y);
        a0 = fmaf(w0, blo(u0.x), a0); a1 = fmaf(w0, bhi(u0.x), a1);
        a2 = fmaf(w0, blo(u0.y), a2); a3 = fmaf(w0, bhi(u0.y), a3);
        a4 = fmaf(w0, blo(u0.z), a4); a5 = fmaf(w0, bhi(u0.z), a5);
        a6 = fmaf(w0, blo(u0.w), a6); a7 = fmaf(w0, bhi(u0.w), a7);
    }
    const float di = dinv[nd];
    uint4 us = *(const uint4*)(h + (size_t)nd * K + 8 * cho);
    float4 bv0 = *(const float4*)(bias + 8 * cho);
    float4 bv1 = *(const float4*)(bias + 8 * cho + 4);
    float o0 = fmaf(di, a0 + blo(us.x), bv0.x);
    float o1 = fmaf(di, a1 + bhi(us.x), bv0.y);
    float o2 = fmaf(di, a2 + blo(us.y), bv0.z);
    float o3 = fmaf(di, a3 + bhi(us.y), bv0.w);
    float o4 = fmaf(di, a4 + blo(us.z), bv1.x);
    float o5 = fmaf(di, a5 + bhi(us.z), bv1.y);
    float o6 = fmaf(di, a6 + blo(us.w), bv1.z);
    float o7 = fmaf(di, a7 + bhi(us.w), bv1.w);
    o0 = fmaxf(o0, 0.f); o1 = fmaxf(o1, 0.f); o2 = fmaxf(o2, 0.f); o3 = fmaxf(o3, 0.f);
    o4 = fmaxf(o4, 0.f); o5 = fmaxf(o5, 0.f); o6 = fmaxf(o6, 0.f); o7 = fmaxf(o7, 0.f);
    if (EPI == 0) {
        uint4 pk;
        pk.x = (unsigned)__builtin_bit_cast(unsigned short, (__bf16)o0) |
               ((unsigned)__builtin_bit_cast(unsigned short, (__bf16)o1) << 16);
        pk.y = (unsigned)__builtin_bit_cast(unsigned short, (__bf16)o2) |
               ((unsigned)__builtin_bit_cast(unsigned short, (__bf16)o3) << 16);
        pk.z = (unsigned)__builtin_bit_cast(unsigned short, (__bf16)o4) |
               ((unsigned)__builtin_bit_cast(unsigned short, (__bf16)o5) << 16);
        pk.w = (unsigned)__builtin_bit_cast(unsigned short, (__bf16)o6) |
               ((unsigned)__builtin_bit_cast(unsigned short, (__bf16)o7) << 16);
        *(uint4*)((unsigned*)outv + (size_t)nd * (K / 2) + 4 * cho) = pk;
    } else {
        float4 wv0 = *(const float4*)(W3 + 8 * cho);
        float4 wv1 = *(const float4*)(W3 + 8 * cho + 4);
        float part = o0 * wv0.x + o1 * wv0.y + o2 * wv0.z + o3 * wv0.w
                   + o4 * wv1.x + o5 * wv1.y + o6 * wv1.z + o7 * wv1.w;
#pragma unroll
        for (int d = SUB / 2; d >= 1; d >>= 1) part += __shfl_xor(part, d, SUB);
        if (cho == 0) ((float*)outv)[nd] = di * part;   // h3' = dinv*h3
    }
}

// output prop: K=1, f32 h3' (pre-scaled by dinv)
__global__ __launch_bounds__(256) void k_prop1(const int* __restrict__ offs,
                                               const int2* __restrict__ csrp,
                                               const float* __restrict__ h,
                                               const float* __restrict__ dinv,
                                               const float* __restrict__ bias,
                                               float* __restrict__ out, int n) {
    long nd = (long)blockIdx.x * BLK + threadIdx.x;
    if (nd >= n) return;
    const int j0 = offs[nd], j1 = offs[nd + 1];
    float acc = 0.f;
    int j = j0;
    for (; j + 3 < j1; j += 4) {
        int2 p0 = csrp[j];
        int2 p1 = csrp[j + 1];
        int2 p2 = csrp[j + 2];
        int2 p3 = csrp[j + 3];
        acc = fmaf(__int_as_float(p0.y), h[p0.x], acc);
        acc = fmaf(__int_as_float(p1.y), h[p1.x], acc);
        acc = fmaf(__int_as_float(p2.y), h[p2.x], acc);
        acc = fmaf(__int_as_float(p3.y), h[p3.x], acc);
    }
    for (; j < j1; ++j) {
        int2 p0 = csrp[j];
        acc = fmaf(__int_as_float(p0.y), h[p0.x], acc);
    }
    const float di = dinv[nd];
    out[nd] = fmaf(di, acc + h[nd], bias[0]);
}

// ---------------------------------------------------------------- launch
extern "C" void kernel_launch(void* const* d_in, const int* in_sizes, int n_in,
                              void* d_out, int out_size, void* d_ws, size_t ws_size,
                              hipStream_t stream) {
    const float* x  = (const float*)d_in[0];
    const void*  ei = d_in[1];
    const float* ew = (const float*)d_in[2];
    const float* W1 = (const float*)d_in[3];
    const float* b1 = (const float*)d_in[4];
    const float* W2 = (const float*)d_in[5];
    const float* b2 = (const float*)d_in[6];
    const float* W3 = (const float*)d_in[7];
    const float* b3 = (const float*)d_in[8];
    float* out = (float*)d_out;

    const int n = in_sizes[0] / 512;
    const int e = in_sizes[2];
    const int nb = (n + 127) >> 7;

    char* ws = (char*)d_ws;
    size_t off = 0;
    auto alloc = [&](size_t bytes) {
        void* p = ws + off;
        off = (off + bytes + 255) & ~(size_t)255;
        return p;
    };
    int2*   binned   = (int2*)  alloc((size_t)e * 8);   // aliased as hbuf1 after k_build
    __bf16* hbuf1    = (__bf16*)binned;                 // n*64*2 = 12.8MB <= e*8
    int*    bkt_cnt  = (int*)   alloc((size_t)(MAXNB + 1) * 4);
    int*    blkbase  = (int*)   alloc((size_t)NBLKBIN * MAXNB * 4);   // 2 MB
    int*    offs     = (int*)   alloc((size_t)(n + 1) * 4);
    int2*   csrp     = (int2*)  alloc((size_t)e * 8);
    float*  dinv     = (float*) alloc((size_t)n * 4);
    __bf16* pb64     = (__bf16*)alloc((size_t)n * 64 * 2);  // relu'd prop1 out (layer2 in)
    __bf16* hbuf2    = (__bf16*)alloc((size_t)n * 32 * 2);  // gemm2 out (scaled)
    float*  h3       = (float*) alloc((size_t)n * 4);       // fused prop2+lin3 out (scaled)
    __bf16* Wtf      = (__bf16*)alloc((size_t)512 * 64 * 2);
    __bf16* Wtf2     = (__bf16*)alloc((size_t)64 * 32 * 2);
    (void)ws_size; (void)n_in; (void)out_size;

    const int gb_n = (n + BLK - 1) / BLK;

    // ---- prep + CSR build (single-pass scatter; bucket offsets via in-LDS prefix)
    k_prep<<<18, 256, 0, stream>>>(W1, W2, Wtf, Wtf2, bkt_cnt, nb);
    k_binhist<<<NBLKBIN, 256, 0, stream>>>(ei, e, bkt_cnt, blkbase, nb);
    k_binscatter<<<NBLKBIN, 256, 0, stream>>>(ei, ew, e, bkt_cnt, blkbase, binned, nb);
    k_build<<<nb, 256, 0, stream>>>(bkt_cnt, binned, dinv, offs, csrp, n, e, nb);

    // ---- layer 1: 512 -> 64 (bf16 MFMA 64 rows/wave, h'=dinv*h; hbuf1 aliases binned)
    k_gemm1_mfma<<<(n + 255) / 256, 256, 0, stream>>>(x, Wtf, dinv, hbuf1, n);
    k_prop_bf<64, 0><<<(n + 31) / 32, 256, 0, stream>>>(offs, csrp, hbuf1, dinv, b1, nullptr, pb64, n);

    // ---- layer 2: 64 -> 32 (bf16 MFMA, scaled), prop fused with lin3 -> h3'
    k_gemm2_mfma<<<(n + 63) / 64, 256, 0, stream>>>(pb64, Wtf2, dinv, hbuf2, n);
    k_prop_bf<32, 1><<<(n + 63) / 64, 256, 0, stream>>>(offs, csrp, hbuf2, dinv, b2, W3, h3, n);

    // ---- layer 3 propagation -> out
    k_prop1<<<gb_n, BLK, 0, stream>>>(offs, csrp, h3, dinv, b3, out, n);
}

// Round 17
// 316.924 us; speedup vs baseline: 1.0119x; 1.0119x over previous
//
#include <hip/hip_runtime.h>

constexpr int BLK = 256;
constexpr int NBLKBIN = 512;      // blocks for binning passes
constexpr int MAXNB   = 1024;     // max buckets (128 dst each -> n <= 131072)

typedef __bf16 bf16x8 __attribute__((ext_vector_type(8)));
typedef float  f32x4  __attribute__((ext_vector_type(4)));

__device__ __forceinline__ float blo(unsigned u) { return __uint_as_float(u << 16); }
__device__ __forceinline__ float bhi(unsigned u) { return __uint_as_float(u & 0xffff0000u); }

__device__ __forceinline__ int detect64(const void* ei) {
    const int* p = (const int*)ei;
    int is64 = 1;
#pragma unroll
    for (int i = 0; i < 16; ++i)
        if (p[2 * i + 1] != 0) is64 = 0;
    return is64;
}

__device__ __forceinline__ int load_idx(const void* ei, size_t pos, int is64) {
    if (is64) return (int)((const long long*)ei)[pos];
    return ((const int*)ei)[pos];
}

// ---------------------------------------------------------------- prep: weights -> frag bf16, zero bkt_cnt
__global__ void k_prep(const float* __restrict__ W1, const float* __restrict__ W2,
                       __bf16* __restrict__ Wtf, __bf16* __restrict__ Wtf2,
                       int* __restrict__ bkt_cnt, int nb) {
    const int b = blockIdx.x;
    const int t = threadIdx.x;
    if (b < 16) {                         // W1 [512][64] -> Wtf (4096 frags of 8)
        int i = b * 256 + t;
        int lane = i & 63;
        int tt   = (i >> 6) & 3;
        int k0c  = i >> 8;
        int col  = tt * 16 + (lane & 15);
        int kbase = k0c * 32 + (lane >> 4) * 8;
        bf16x8 v;
#pragma unroll
        for (int j = 0; j < 8; ++j) v[j] = (__bf16)W1[(size_t)(kbase + j) * 64 + col];
        *(bf16x8*)(Wtf + (size_t)i * 8) = v;
    } else if (b == 16) {                 // W2 [64][32] -> Wtf2 (256 frags of 8)
        int i = t;
        int lane = i & 63;
        int ct   = i >> 6;
        int tt = ct & 1, chunk = ct >> 1;
        int col  = tt * 16 + (lane & 15);
        int kbase = chunk * 32 + (lane >> 4) * 8;
        bf16x8 v;
#pragma unroll
        for (int j = 0; j < 8; ++j) v[j] = (__bf16)W2[(size_t)(kbase + j) * 32 + col];
        *(bf16x8*)(Wtf2 + (size_t)i * 8) = v;
    } else {                              // zero bucket counters
        for (int i = t; i < nb; i += 256) bkt_cnt[i] = 0;
    }
}

// ---------------------------------------------------------------- B1: bucket histogram; persist per-block bases
__global__ __launch_bounds__(256) void k_binhist(const void* __restrict__ ei, int e,
                                                 int* __restrict__ bucket_cnt,
                                                 int* __restrict__ blkbase, int nb) {
    __shared__ int hist[MAXNB];
    const int t = threadIdx.x;
    for (int b = t; b < nb; b += 256) hist[b] = 0;
    __syncthreads();
    const int is64 = detect64(ei);
    const int chunk = (e + NBLKBIN - 1) / NBLKBIN;
    const int i0 = blockIdx.x * chunk;
    const int i1 = min(e, i0 + chunk);
    for (int i = i0 + t; i < i1; i += 256) {
        int dst = load_idx(ei, (size_t)e + i, is64);
        atomicAdd(&hist[dst >> 7], 1);
    }
    __syncthreads();
    int* myb = blkbase + (size_t)blockIdx.x * MAXNB;
    for (int b = t; b < nb; b += 256) {
        int c = hist[b];
        int base = 0;
        if (c) base = atomicAdd(&bucket_cnt[b], c);
        myb[b] = base;
    }
}

// helper: block-wide prefix over bkt_cnt -> pfx[MAXNB] (inclusive)
__device__ __forceinline__ void bucket_prefix(const int* __restrict__ bkt_cnt, int nb,
                                              int* scn, int* pfx) {
    const int t = threadIdx.x;
    const int base = t * 4;
    int v[4]; int s = 0;
#pragma unroll
    for (int k = 0; k < 4; ++k) {
        int i = base + k;
        v[k] = (i < nb) ? bkt_cnt[i] : 0;
        s += v[k];
    }
    scn[t] = s;
    __syncthreads();
    for (int d = 1; d < 256; d <<= 1) {
        int x = (t >= d) ? scn[t - d] : 0;
        __syncthreads();
        scn[t] += x;
        __syncthreads();
    }
    int run = (t == 0) ? 0 : scn[t - 1];
#pragma unroll
    for (int k = 0; k < 4; ++k) {
        run += v[k];
        pfx[base + k] = run;            // inclusive
    }
    __syncthreads();
}

// ---------------------------------------------------------------- B3: SINGLE-PASS scatter
__global__ __launch_bounds__(256) void k_binscatter(const void* __restrict__ ei,
                                                    const float* __restrict__ ew, int e,
                                                    const int* __restrict__ bkt_cnt,
                                                    const int* __restrict__ blkbase,
                                                    int2* __restrict__ binned, int nb) {
    __shared__ int scn[256];
    __shared__ int hist[MAXNB];
    const int t = threadIdx.x;
    const int base = t * 4;
    int v[4]; int s = 0;
#pragma unroll
    for (int k = 0; k < 4; ++k) {
        int i = base + k;
        v[k] = (i < nb) ? bkt_cnt[i] : 0;
        s += v[k];
    }
    scn[t] = s;
    __syncthreads();
    for (int d = 1; d < 256; d <<= 1) {
        int x = (t >= d) ? scn[t - d] : 0;
        __syncthreads();
        scn[t] += x;
        __syncthreads();
    }
    int excl = (t == 0) ? 0 : scn[t - 1];
    const int* myb = blkbase + (size_t)blockIdx.x * MAXNB;
#pragma unroll
    for (int k = 0; k < 4; ++k) {
        int i = base + k;
        if (i < nb) hist[i] = excl + myb[i];
        excl += v[k];
    }
    __syncthreads();
    const int is64 = detect64(ei);
    const int chunk = (e + NBLKBIN - 1) / NBLKBIN;
    const int i0 = blockIdx.x * chunk;
    const int i1 = min(e, i0 + chunk);
    for (int i = i0 + t; i < i1; i += 256) {
        int dst = load_idx(ei, (size_t)e + i, is64);
        int src = load_idx(ei, (size_t)i, is64);
        float w = ew[i];
        int bin = dst >> 7;
        int pos = atomicAdd(&hist[bin], 1);
        binned[pos] = make_int2(src | ((dst & 127) << 20), __float_as_int(w));
    }
}

// ---------------------------------------------------------------- B4: fused build
__global__ __launch_bounds__(256) void k_build(const int* __restrict__ bkt_cnt,
                                               const int2* __restrict__ binned,
                                               float* __restrict__ dinv,
                                               int* __restrict__ offs,
                                               int2* __restrict__ csrp, int n, int e, int nb) {
    __shared__ int                scn[256];
    __shared__ int                pfx[MAXNB];
    __shared__ int                icnt[128];
    __shared__ unsigned long long facc[128];
    __shared__ int                scn2[128];
    __shared__ int                cur[128];
    const int t = threadIdx.x;
    const int b = blockIdx.x;
    bucket_prefix(bkt_cnt, nb, scn, pfx);
    const int j0 = (b == 0) ? 0 : pfx[b - 1];
    const int j1 = pfx[b];
    if (t < 128) { icnt[t] = 0; facc[t] = 0ull; }
    __syncthreads();
    const float SCALE = 1099511627776.f;      // 2^40
    for (int j = j0 + t; j < j1; j += 256) {
        int2 p = binned[j];
        int dl = ((unsigned)p.x) >> 20;
        atomicAdd(&icnt[dl], 1);
        atomicAdd(&facc[dl], (unsigned long long)(__int_as_float(p.y) * SCALE));
    }
    __syncthreads();
    if (t < 128) {
        int nd = b * 128 + t;
        if (nd < n) dinv[nd] = rsqrtf(fmaf((float)facc[t], 1.f / 1099511627776.f, 1.0f));
        scn2[t] = icnt[t];
    }
    __syncthreads();
    for (int d = 1; d < 128; d <<= 1) {
        int x = 0;
        if (t < 128 && t >= d) x = scn2[t - d];
        __syncthreads();
        if (t < 128) scn2[t] += x;
        __syncthreads();
    }
    if (t < 128) {
        int excl = (t == 0) ? 0 : scn2[t - 1];
        int abs0 = j0 + excl;
        cur[t] = abs0;
        int nd = b * 128 + t;
        if (nd < n) offs[nd] = abs0;
    }
    if (b == 0 && t == 0) offs[n] = e;
    __syncthreads();
    for (int j = j0 + t; j < j1; j += 256) {
        int2 p = binned[j];
        int dl  = ((unsigned)p.x) >> 20;
        int src = p.x & 0xFFFFF;
        int pos = atomicAdd(&cur[dl], 1);
        csrp[pos] = make_int2(src, p.y);      // raw weight; dinv folded into h'
    }
}

// ---------------------------------------------------------------- GEMM1: bf16 MFMA, 32 rows/wave, h' = dinv*h
__global__ __launch_bounds__(256) void k_gemm1_mfma(const float* __restrict__ X,
                                                    const __bf16* __restrict__ Wtf,
                                                    const float* __restrict__ dinv,
                                                    __bf16* __restrict__ H, int nrows) {
    const int wave = threadIdx.x >> 6;
    const int lane = threadIdx.x & 63;
    const int l15  = lane & 15;
    const int lq   = lane >> 4;
    const long rbase = (long)blockIdx.x * 128 + wave * 32;

    long ar0 = rbase + l15;      if (ar0 >= nrows) ar0 = nrows - 1;
    long ar1 = rbase + 16 + l15; if (ar1 >= nrows) ar1 = nrows - 1;
    const float4* x0 = (const float4*)(X + (size_t)ar0 * 512) + lq * 2;
    const float4* x1 = (const float4*)(X + (size_t)ar1 * 512) + lq * 2;

    f32x4 acc[2][4];
#pragma unroll
    for (int r = 0; r < 2; ++r)
#pragma unroll
        for (int t = 0; t < 4; ++t) acc[r][t] = f32x4{0.f, 0.f, 0.f, 0.f};

    float4 pa[2][2][2];  // [stage][row][half]
#pragma unroll
    for (int s = 0; s < 2; ++s) {
        pa[s][0][0] = x0[s * 8]; pa[s][0][1] = x0[s * 8 + 1];
        pa[s][1][0] = x1[s * 8]; pa[s][1][1] = x1[s * 8 + 1];
    }

#pragma unroll
    for (int k0c = 0; k0c < 16; ++k0c) {
        const int s = k0c & 1;
        float4 a00 = pa[s][0][0], a01 = pa[s][0][1];
        float4 a10 = pa[s][1][0], a11 = pa[s][1][1];
        if (k0c + 2 < 16) {
            pa[s][0][0] = x0[(k0c + 2) * 8]; pa[s][0][1] = x0[(k0c + 2) * 8 + 1];
            pa[s][1][0] = x1[(k0c + 2) * 8]; pa[s][1][1] = x1[(k0c + 2) * 8 + 1];
        }
        bf16x8 af0, af1;
        af0[0] = (__bf16)a00.x; af0[1] = (__bf16)a00.y; af0[2] = (__bf16)a00.z; af0[3] = (__bf16)a00.w;
        af0[4] = (__bf16)a01.x; af0[5] = (__bf16)a01.y; af0[6] = (__bf16)a01.z; af0[7] = (__bf16)a01.w;
        af1[0] = (__bf16)a10.x; af1[1] = (__bf16)a10.y; af1[2] = (__bf16)a10.z; af1[3] = (__bf16)a10.w;
        af1[4] = (__bf16)a11.x; af1[5] = (__bf16)a11.y; af1[6] = (__bf16)a11.z; af1[7] = (__bf16)a11.w;
#pragma unroll
        for (int t = 0; t < 4; ++t) {
            bf16x8 bf_ = *(const bf16x8*)(Wtf + ((size_t)(k0c * 4 + t) * 64 + lane) * 8);
            acc[0][t] = __builtin_amdgcn_mfma_f32_16x16x32_bf16(af0, bf_, acc[0][t], 0, 0, 0);
            acc[1][t] = __builtin_amdgcn_mfma_f32_16x16x32_bf16(af1, bf_, acc[1][t], 0, 0, 0);
        }
    }
#pragma unroll
    for (int rr = 0; rr < 2; ++rr)
#pragma unroll
    for (int r = 0; r < 4; ++r) {
        long row = rbase + rr * 16 + lq * 4 + r;
        if (row < nrows) {
            float dv = dinv[row];
#pragma unroll
            for (int t = 0; t < 4; ++t)
                H[(size_t)row * 64 + t * 16 + l15] = (__bf16)(acc[rr][t][r] * dv);
        }
    }
}

// ---------------------------------------------------------------- GEMM2: 64 -> 32 bf16 MFMA, h' = dinv*h
__global__ __launch_bounds__(256) void k_gemm2_mfma(const __bf16* __restrict__ A,
                                                    const __bf16* __restrict__ Wtf2,
                                                    const float* __restrict__ dinv,
                                                    __bf16* __restrict__ H, int nrows) {
    const int wave = threadIdx.x >> 6;
    const int lane = threadIdx.x & 63;
    const int l15  = lane & 15;
    const int lq   = lane >> 4;
    const long rbase = (long)blockIdx.x * 64 + wave * 16;

    long arow = rbase + l15;
    if (arow >= nrows) arow = nrows - 1;

    f32x4 acc[2] = {{0.f,0.f,0.f,0.f},{0.f,0.f,0.f,0.f}};
#pragma unroll
    for (int c = 0; c < 2; ++c) {
        bf16x8 af = *(const bf16x8*)(A + (size_t)arow * 64 + c * 32 + lq * 8);
#pragma unroll
        for (int t = 0; t < 2; ++t) {
            bf16x8 bf_ = *(const bf16x8*)(Wtf2 + ((size_t)(c * 2 + t) * 64 + lane) * 8);
            acc[t] = __builtin_amdgcn_mfma_f32_16x16x32_bf16(af, bf_, acc[t], 0, 0, 0);
        }
    }
#pragma unroll
    for (int r = 0; r < 4; ++r) {
        long row = rbase + lq * 4 + r;
        if (row < nrows) {
            float dv = dinv[row];
#pragma unroll
            for (int t = 0; t < 2; ++t)
                H[(size_t)row * 32 + t * 16 + l15] = (__bf16)(acc[t][r] * dv);
        }
    }
}

// ---------------------------------------------------------------- propagation (CSR gather, bf16 h', 16B/lane)
// h' = dinv*h; out = di*(sum w*h'[src] + h'[nd]) + b ; lane owns 8 channels (16B load)
// EPI 0: relu -> packed bf16    EPI 1: fused lin3 -> h3' = dinv * (relu(o)·W3)
template <int K, int EPI>
__global__ __launch_bounds__(256) void k_prop_bf(const int* __restrict__ offs,
                                                 const int2* __restrict__ csrp,
                                                 const __bf16* __restrict__ hb,
                                                 const float* __restrict__ dinv,
                                                 const float* __restrict__ bias,
                                                 const float* __restrict__ W3,
                                                 void* __restrict__ outv, int n) {
    constexpr int SUB = K / 8;           // lanes per node (8 for K=64, 4 for K=32)
    constexpr int NPW = 64 / SUB;        // nodes per wave
    constexpr int NPB = 4 * NPW;         // nodes per block
    const int t    = threadIdx.x;
    const int lane = t & 63;
    const int wave = t >> 6;
    const int cho  = lane & (SUB - 1);   // channel-octet index
    const int sub  = lane / SUB;
    const long nd  = (long)blockIdx.x * NPB + wave * NPW + sub;
    if (nd >= n) return;

    const unsigned short* h = (const unsigned short*)hb;
    const int j0 = offs[nd], j1 = offs[nd + 1];
    float a0 = 0.f, a1 = 0.f, a2 = 0.f, a3 = 0.f;
    float a4 = 0.f, a5 = 0.f, a6 = 0.f, a7 = 0.f;
    int j = j0;
    for (; j + 3 < j1; j += 4) {
        int2 p0 = csrp[j];
        int2 p1 = csrp[j + 1];
        int2 p2 = csrp[j + 2];
        int2 p3 = csrp[j + 3];
        uint4 u0 = *(const uint4*)(h + (size_t)p0.x * K + 8 * cho);
        uint4 u1 = *(const uint4*)(h + (size_t)p1.x * K + 8 * cho);
        uint4 u2 = *(const uint4*)(h + (size_t)p2.x * K + 8 * cho);
        uint4 u3 = *(const uint4*)(h + (size_t)p3.x * K + 8 * cho);
        float w0 = __int_as_float(p0.y), w1 = __int_as_float(p1.y);
        float w2 = __int_as_float(p2.y), w3 = __int_as_float(p3.y);
        a0 = fmaf(w0, blo(u0.x), a0); a1 = fmaf(w0, bhi(u0.x), a1);
        a2 = fmaf(w0, blo(u0.y), a2); a3 = fmaf(w0, bhi(u0.y), a3);
        a4 = fmaf(w0, blo(u0.z), a4); a5 = fmaf(w0, bhi(u0.z), a5);
        a6 = fmaf(w0, blo(u0.w), a6); a7 = fmaf(w0, bhi(u0.w), a7);
        a0 = fmaf(w1, blo(u1.x), a0); a1 = fmaf(w1, bhi(u1.x), a1);
        a2 = fmaf(w1, blo(u1.y), a2); a3 = fmaf(w1, bhi(u1.y), a3);
        a4 = fmaf(w1, blo(u1.z), a4); a5 = fmaf(w1, bhi(u1.z), a5);
        a6 = fmaf(w1, blo(u1.w), a6); a7 = fmaf(w1, bhi(u1.w), a7);
        a0 = fmaf(w2, blo(u2.x), a0); a1 = fmaf(w2, bhi(u2.x), a1);
        a2 = fmaf(w2, blo(u2.y), a2); a3 = fmaf(w2, bhi(u2.y), a3);
        a4 = fmaf(w2, blo(u2.z), a4); a5 = fmaf(w2, bhi(u2.z), a5);
        a6 = fmaf(w2, blo(u2.w), a6); a7 = fmaf(w2, bhi(u2.w), a7);
        a0 = fmaf(w3, blo(u3.x), a0); a1 = fmaf(w3, bhi(u3.x), a1);
        a2 = fmaf(w3, blo(u3.y), a2); a3 = fmaf(w3, bhi(u3.y), a3);
        a4 = fmaf(w3, blo(u3.z), a4); a5 = fmaf(w3, bhi(u3.z), a5);
        a6 = fmaf(w3, blo(u3.w), a6); a7 = fmaf(w3, bhi(u3.w), a7);
    }
    for (; j < j1; ++j) {
        int2 p0 = csrp[j];
        uint4 u0 = *(const uint4*)(h + (size_t)p0.x * K + 8 * cho);
        float w0 = __int_as_float(p0.y);
        a0 = fmaf(w0, blo(u0.x), a0); a1 = fmaf(w0, bhi(u0.x), a1);
        a2 = fmaf(w0, blo(u0.y), a2); a3 = fmaf(w0, bhi(u0.y), a3);
        a4 = fmaf(w0, blo(u0.z), a4); a5 = fmaf(w0, bhi(u0.z), a5);
        a6 = fmaf(w0, blo(u0.w), a6); a7 = fmaf(w0, bhi(u0.w), a7);
    }
    const float di = dinv[nd];
    uint4 us = *(const uint4*)(h + (size_t)nd * K + 8 * cho);
    float4 bv0 = *(const float4*)(bias + 8 * cho);
    float4 bv1 = *(const float4*)(bias + 8 * cho + 4);
    float o0 = fmaf(di, a0 + blo(us.x), bv0.x);
    float o1 = fmaf(di, a1 + bhi(us.x), bv0.y);
    float o2 = fmaf(di, a2 + blo(us.y), bv0.z);
    float o3 = fmaf(di, a3 + bhi(us.y), bv0.w);
    float o4 = fmaf(di, a4 + blo(us.z), bv1.x);
    float o5 = fmaf(di, a5 + bhi(us.z), bv1.y);
    float o6 = fmaf(di, a6 + blo(us.w), bv1.z);
    float o7 = fmaf(di, a7 + bhi(us.w), bv1.w);
    o0 = fmaxf(o0, 0.f); o1 = fmaxf(o1, 0.f); o2 = fmaxf(o2, 0.f); o3 = fmaxf(o3, 0.f);
    o4 = fmaxf(o4, 0.f); o5 = fmaxf(o5, 0.f); o6 = fmaxf(o6, 0.f); o7 = fmaxf(o7, 0.f);
    if (EPI == 0) {
        uint4 pk;
        pk.x = (unsigned)__builtin_bit_cast(unsigned short, (__bf16)o0) |
               ((unsigned)__builtin_bit_cast(unsigned short, (__bf16)o1) << 16);
        pk.y = (unsigned)__builtin_bit_cast(unsigned short, (__bf16)o2) |
               ((unsigned)__builtin_bit_cast(unsigned short, (__bf16)o3) << 16);
        pk.z = (unsigned)__builtin_bit_cast(unsigned short, (__bf16)o4) |
               ((unsigned)__builtin_bit_cast(unsigned short, (__bf16)o5) << 16);
        pk.w = (unsigned)__builtin_bit_cast(unsigned short, (__bf16)o6) |
               ((unsigned)__builtin_bit_cast(unsigned short, (__bf16)o7) << 16);
        *(uint4*)((unsigned*)outv + (size_t)nd * (K / 2) + 4 * cho) = pk;
    } else {
        float4 wv0 = *(const float4*)(W3 + 8 * cho);
        float4 wv1 = *(const float4*)(W3 + 8 * cho + 4);
        float part = o0 * wv0.x + o1 * wv0.y + o2 * wv0.z + o3 * wv0.w
                   + o4 * wv1.x + o5 * wv1.y + o6 * wv1.z + o7 * wv1.w;
#pragma unroll
        for (int d = SUB / 2; d >= 1; d >>= 1) part += __shfl_xor(part, d, SUB);
        if (cho == 0) ((float*)outv)[nd] = di * part;   // h3' = dinv*h3
    }
}

// output prop: K=1, f32 h3' (pre-scaled by dinv)
__global__ __launch_bounds__(256) void k_prop1(const int* __restrict__ offs,
                                               const int2* __restrict__ csrp,
                                               const float* __restrict__ h,
                                               const float* __restrict__ dinv,
                                               const float* __restrict__ bias,
                                               float* __restrict__ out, int n) {
    long nd = (long)blockIdx.x * BLK + threadIdx.x;
    if (nd >= n) return;
    const int j0 = offs[nd], j1 = offs[nd + 1];
    float acc = 0.f;
    int j = j0;
    for (; j + 3 < j1; j += 4) {
        int2 p0 = csrp[j];
        int2 p1 = csrp[j + 1];
        int2 p2 = csrp[j + 2];
        int2 p3 = csrp[j + 3];
        acc = fmaf(__int_as_float(p0.y), h[p0.x], acc);
        acc = fmaf(__int_as_float(p1.y), h[p1.x], acc);
        acc = fmaf(__int_as_float(p2.y), h[p2.x], acc);
        acc = fmaf(__int_as_float(p3.y), h[p3.x], acc);
    }
    for (; j < j1; ++j) {
        int2 p0 = csrp[j];
        acc = fmaf(__int_as_float(p0.y), h[p0.x], acc);
    }
    const float di = dinv[nd];
    out[nd] = fmaf(di, acc + h[nd], bias[0]);
}

// ---------------------------------------------------------------- launch
extern "C" void kernel_launch(void* const* d_in, const int* in_sizes, int n_in,
                              void* d_out, int out_size, void* d_ws, size_t ws_size,
                              hipStream_t stream) {
    const float* x  = (const float*)d_in[0];
    const void*  ei = d_in[1];
    const float* ew = (const float*)d_in[2];
    const float* W1 = (const float*)d_in[3];
    const float* b1 = (const float*)d_in[4];
    const float* W2 = (const float*)d_in[5];
    const float* b2 = (const float*)d_in[6];
    const float* W3 = (const float*)d_in[7];
    const float* b3 = (const float*)d_in[8];
    float* out = (float*)d_out;

    const int n = in_sizes[0] / 512;
    const int e = in_sizes[2];
    const int nb = (n + 127) >> 7;

    char* ws = (char*)d_ws;
    size_t off = 0;
    auto alloc = [&](size_t bytes) {
        void* p = ws + off;
        off = (off + bytes + 255) & ~(size_t)255;
        return p;
    };
    int2*   binned   = (int2*)  alloc((size_t)e * 8);   // aliased as hbuf1 after k_build
    __bf16* hbuf1    = (__bf16*)binned;                 // n*64*2 = 12.8MB <= e*8
    int*    bkt_cnt  = (int*)   alloc((size_t)(MAXNB + 1) * 4);
    int*    blkbase  = (int*)   alloc((size_t)NBLKBIN * MAXNB * 4);   // 2 MB
    int*    offs     = (int*)   alloc((size_t)(n + 1) * 4);
    int2*   csrp     = (int2*)  alloc((size_t)e * 8);
    float*  dinv     = (float*) alloc((size_t)n * 4);
    __bf16* pb64     = (__bf16*)alloc((size_t)n * 64 * 2);  // relu'd prop1 out (layer2 in)
    __bf16* hbuf2    = (__bf16*)alloc((size_t)n * 32 * 2);  // gemm2 out (scaled)
    float*  h3       = (float*) alloc((size_t)n * 4);       // fused prop2+lin3 out (scaled)
    __bf16* Wtf      = (__bf16*)alloc((size_t)512 * 64 * 2);
    __bf16* Wtf2     = (__bf16*)alloc((size_t)64 * 32 * 2);
    (void)ws_size; (void)n_in; (void)out_size;

    const int gb_n = (n + BLK - 1) / BLK;

    // ---- prep + CSR build (single-pass scatter; bucket offsets via in-LDS prefix)
    k_prep<<<18, 256, 0, stream>>>(W1, W2, Wtf, Wtf2, bkt_cnt, nb);
    k_binhist<<<NBLKBIN, 256, 0, stream>>>(ei, e, bkt_cnt, blkbase, nb);
    k_binscatter<<<NBLKBIN, 256, 0, stream>>>(ei, ew, e, bkt_cnt, blkbase, binned, nb);
    k_build<<<nb, 256, 0, stream>>>(bkt_cnt, binned, dinv, offs, csrp, n, e, nb);

    // ---- layer 1: 512 -> 64 (bf16 MFMA 32 rows/wave, h'=dinv*h; hbuf1 aliases binned)
    k_gemm1_mfma<<<(n + 127) / 128, 256, 0, stream>>>(x, Wtf, dinv, hbuf1, n);
    k_prop_bf<64, 0><<<(n + 31) / 32, 256, 0, stream>>>(offs, csrp, hbuf1, dinv, b1, nullptr, pb64, n);

    // ---- layer 2: 64 -> 32 (bf16 MFMA, scaled), prop fused with lin3 -> h3'
    k_gemm2_mfma<<<(n + 63) / 64, 256, 0, stream>>>(pb64, Wtf2, dinv, hbuf2, n);
    k_prop_bf<32, 1><<<(n + 63) / 64, 256, 0, stream>>>(offs, csrp, hbuf2, dinv, b2, W3, h3, n);

    // ---- layer 3 propagation -> out
    k_prop1<<<gb_n, BLK, 0, stream>>>(offs, csrp, h3, dinv, b3, out, n);
}

// Round 18
// 313.047 us; speedup vs baseline: 1.0245x; 1.0124x over previous
//
#include <hip/hip_runtime.h>

constexpr int BLK = 256;
constexpr int NBLKBIN = 512;      // blocks for binning passes
constexpr int MAXNB   = 1024;     // max buckets (128 dst each -> n <= 131072)

typedef __bf16 bf16x8 __attribute__((ext_vector_type(8)));
typedef float  f32x4  __attribute__((ext_vector_type(4)));

__device__ __forceinline__ float blo(unsigned u) { return __uint_as_float(u << 16); }
__device__ __forceinline__ float bhi(unsigned u) { return __uint_as_float(u & 0xffff0000u); }

__device__ __forceinline__ int detect64(const void* ei) {
    const int* p = (const int*)ei;
    int is64 = 1;
#pragma unroll
    for (int i = 0; i < 16; ++i)
        if (p[2 * i + 1] != 0) is64 = 0;
    return is64;
}

__device__ __forceinline__ int load_idx(const void* ei, size_t pos, int is64) {
    if (is64) return (int)((const long long*)ei)[pos];
    return ((const int*)ei)[pos];
}

// ---------------------------------------------------------------- prep: weights -> frag bf16, zero bkt_cnt
__global__ void k_prep(const float* __restrict__ W1, const float* __restrict__ W2,
                       __bf16* __restrict__ Wtf, __bf16* __restrict__ Wtf2,
                       int* __restrict__ bkt_cnt, int nb) {
    const int b = blockIdx.x;
    const int t = threadIdx.x;
    if (b < 16) {                         // W1 [512][64] -> Wtf (4096 frags of 8)
        int i = b * 256 + t;
        int lane = i & 63;
        int tt   = (i >> 6) & 3;
        int k0c  = i >> 8;
        int col  = tt * 16 + (lane & 15);
        int kbase = k0c * 32 + (lane >> 4) * 8;
        bf16x8 v;
#pragma unroll
        for (int j = 0; j < 8; ++j) v[j] = (__bf16)W1[(size_t)(kbase + j) * 64 + col];
        *(bf16x8*)(Wtf + (size_t)i * 8) = v;
    } else if (b == 16) {                 // W2 [64][32] -> Wtf2 (256 frags of 8)
        int i = t;
        int lane = i & 63;
        int ct   = i >> 6;
        int tt = ct & 1, chunk = ct >> 1;
        int col  = tt * 16 + (lane & 15);
        int kbase = chunk * 32 + (lane >> 4) * 8;
        bf16x8 v;
#pragma unroll
        for (int j = 0; j < 8; ++j) v[j] = (__bf16)W2[(size_t)(kbase + j) * 32 + col];
        *(bf16x8*)(Wtf2 + (size_t)i * 8) = v;
    } else {                              // zero bucket counters
        for (int i = t; i < nb; i += 256) bkt_cnt[i] = 0;
    }
}

// ---------------------------------------------------------------- B1: bucket histogram; persist per-block bases
__global__ __launch_bounds__(256) void k_binhist(const void* __restrict__ ei, int e,
                                                 int* __restrict__ bucket_cnt,
                                                 int* __restrict__ blkbase, int nb) {
    __shared__ int hist[MAXNB];
    const int t = threadIdx.x;
    for (int b = t; b < nb; b += 256) hist[b] = 0;
    __syncthreads();
    const int is64 = detect64(ei);
    const int chunk = (e + NBLKBIN - 1) / NBLKBIN;
    const int i0 = blockIdx.x * chunk;
    const int i1 = min(e, i0 + chunk);
    for (int i = i0 + t; i < i1; i += 256) {
        int dst = load_idx(ei, (size_t)e + i, is64);
        atomicAdd(&hist[dst >> 7], 1);
    }
    __syncthreads();
    int* myb = blkbase + (size_t)blockIdx.x * MAXNB;
    for (int b = t; b < nb; b += 256) {
        int c = hist[b];
        int base = 0;
        if (c) base = atomicAdd(&bucket_cnt[b], c);
        myb[b] = base;
    }
}

// helper: block-wide prefix over bkt_cnt -> pfx[MAXNB] (inclusive)
__device__ __forceinline__ void bucket_prefix(const int* __restrict__ bkt_cnt, int nb,
                                              int* scn, int* pfx) {
    const int t = threadIdx.x;
    const int base = t * 4;
    int v[4]; int s = 0;
#pragma unroll
    for (int k = 0; k < 4; ++k) {
        int i = base + k;
        v[k] = (i < nb) ? bkt_cnt[i] : 0;
        s += v[k];
    }
    scn[t] = s;
    __syncthreads();
    for (int d = 1; d < 256; d <<= 1) {
        int x = (t >= d) ? scn[t - d] : 0;
        __syncthreads();
        scn[t] += x;
        __syncthreads();
    }
    int run = (t == 0) ? 0 : scn[t - 1];
#pragma unroll
    for (int k = 0; k < 4; ++k) {
        run += v[k];
        pfx[base + k] = run;            // inclusive
    }
    __syncthreads();
}

// ---------------------------------------------------------------- B3: SINGLE-PASS scatter
__global__ __launch_bounds__(256) void k_binscatter(const void* __restrict__ ei,
                                                    const float* __restrict__ ew, int e,
                                                    const int* __restrict__ bkt_cnt,
                                                    const int* __restrict__ blkbase,
                                                    int2* __restrict__ binned, int nb) {
    __shared__ int scn[256];
    __shared__ int hist[MAXNB];
    const int t = threadIdx.x;
    const int base = t * 4;
    int v[4]; int s = 0;
#pragma unroll
    for (int k = 0; k < 4; ++k) {
        int i = base + k;
        v[k] = (i < nb) ? bkt_cnt[i] : 0;
        s += v[k];
    }
    scn[t] = s;
    __syncthreads();
    for (int d = 1; d < 256; d <<= 1) {
        int x = (t >= d) ? scn[t - d] : 0;
        __syncthreads();
        scn[t] += x;
        __syncthreads();
    }
    int excl = (t == 0) ? 0 : scn[t - 1];
    const int* myb = blkbase + (size_t)blockIdx.x * MAXNB;
#pragma unroll
    for (int k = 0; k < 4; ++k) {
        int i = base + k;
        if (i < nb) hist[i] = excl + myb[i];
        excl += v[k];
    }
    __syncthreads();
    const int is64 = detect64(ei);
    const int chunk = (e + NBLKBIN - 1) / NBLKBIN;
    const int i0 = blockIdx.x * chunk;
    const int i1 = min(e, i0 + chunk);
    for (int i = i0 + t; i < i1; i += 256) {
        int dst = load_idx(ei, (size_t)e + i, is64);
        int src = load_idx(ei, (size_t)i, is64);
        float w = ew[i];
        int bin = dst >> 7;
        int pos = atomicAdd(&hist[bin], 1);
        binned[pos] = make_int2(src | ((dst & 127) << 20), __float_as_int(w));
    }
}

// ---------------------------------------------------------------- B4: fused build
__global__ __launch_bounds__(256) void k_build(const int* __restrict__ bkt_cnt,
                                               const int2* __restrict__ binned,
                                               float* __restrict__ dinv,
                                               int* __restrict__ offs,
                                               int2* __restrict__ csrp, int n, int e, int nb) {
    __shared__ int                scn[256];
    __shared__ int                pfx[MAXNB];
    __shared__ int                icnt[128];
    __shared__ unsigned long long facc[128];
    __shared__ int                scn2[128];
    __shared__ int                cur[128];
    const int t = threadIdx.x;
    const int b = blockIdx.x;
    bucket_prefix(bkt_cnt, nb, scn, pfx);
    const int j0 = (b == 0) ? 0 : pfx[b - 1];
    const int j1 = pfx[b];
    if (t < 128) { icnt[t] = 0; facc[t] = 0ull; }
    __syncthreads();
    const float SCALE = 1099511627776.f;      // 2^40
    for (int j = j0 + t; j < j1; j += 256) {
        int2 p = binned[j];
        int dl = ((unsigned)p.x) >> 20;
        atomicAdd(&icnt[dl], 1);
        atomicAdd(&facc[dl], (unsigned long long)(__int_as_float(p.y) * SCALE));
    }
    __syncthreads();
    if (t < 128) {
        int nd = b * 128 + t;
        if (nd < n) dinv[nd] = rsqrtf(fmaf((float)facc[t], 1.f / 1099511627776.f, 1.0f));
        scn2[t] = icnt[t];
    }
    __syncthreads();
    for (int d = 1; d < 128; d <<= 1) {
        int x = 0;
        if (t < 128 && t >= d) x = scn2[t - d];
        __syncthreads();
        if (t < 128) scn2[t] += x;
        __syncthreads();
    }
    if (t < 128) {
        int excl = (t == 0) ? 0 : scn2[t - 1];
        int abs0 = j0 + excl;
        cur[t] = abs0;
        int nd = b * 128 + t;
        if (nd < n) offs[nd] = abs0;
    }
    if (b == 0 && t == 0) offs[n] = e;
    __syncthreads();
    for (int j = j0 + t; j < j1; j += 256) {
        int2 p = binned[j];
        int dl  = ((unsigned)p.x) >> 20;
        int src = p.x & 0xFFFFF;
        int pos = atomicAdd(&cur[dl], 1);
        csrp[pos] = make_int2(src, p.y);      // raw weight; dinv folded into h'
    }
}

// ---------------------------------------------------------------- GEMM1: bf16 MFMA, 32 rows/wave, h' = dinv*h
__global__ __launch_bounds__(256) void k_gemm1_mfma(const float* __restrict__ X,
                                                    const __bf16* __restrict__ Wtf,
                                                    const float* __restrict__ dinv,
                                                    __bf16* __restrict__ H, int nrows) {
    const int wave = threadIdx.x >> 6;
    const int lane = threadIdx.x & 63;
    const int l15  = lane & 15;
    const int lq   = lane >> 4;
    const long rbase = (long)blockIdx.x * 128 + wave * 32;

    long ar0 = rbase + l15;      if (ar0 >= nrows) ar0 = nrows - 1;
    long ar1 = rbase + 16 + l15; if (ar1 >= nrows) ar1 = nrows - 1;
    const float4* x0 = (const float4*)(X + (size_t)ar0 * 512) + lq * 2;
    const float4* x1 = (const float4*)(X + (size_t)ar1 * 512) + lq * 2;

    f32x4 acc[2][4];
#pragma unroll
    for (int r = 0; r < 2; ++r)
#pragma unroll
        for (int t = 0; t < 4; ++t) acc[r][t] = f32x4{0.f, 0.f, 0.f, 0.f};

    float4 pa[2][2][2];  // [stage][row][half]
#pragma unroll
    for (int s = 0; s < 2; ++s) {
        pa[s][0][0] = x0[s * 8]; pa[s][0][1] = x0[s * 8 + 1];
        pa[s][1][0] = x1[s * 8]; pa[s][1][1] = x1[s * 8 + 1];
    }

#pragma unroll
    for (int k0c = 0; k0c < 16; ++k0c) {
        const int s = k0c & 1;
        float4 a00 = pa[s][0][0], a01 = pa[s][0][1];
        float4 a10 = pa[s][1][0], a11 = pa[s][1][1];
        if (k0c + 2 < 16) {
            pa[s][0][0] = x0[(k0c + 2) * 8]; pa[s][0][1] = x0[(k0c + 2) * 8 + 1];
            pa[s][1][0] = x1[(k0c + 2) * 8]; pa[s][1][1] = x1[(k0c + 2) * 8 + 1];
        }
        bf16x8 af0, af1;
        af0[0] = (__bf16)a00.x; af0[1] = (__bf16)a00.y; af0[2] = (__bf16)a00.z; af0[3] = (__bf16)a00.w;
        af0[4] = (__bf16)a01.x; af0[5] = (__bf16)a01.y; af0[6] = (__bf16)a01.z; af0[7] = (__bf16)a01.w;
        af1[0] = (__bf16)a10.x; af1[1] = (__bf16)a10.y; af1[2] = (__bf16)a10.z; af1[3] = (__bf16)a10.w;
        af1[4] = (__bf16)a11.x; af1[5] = (__bf16)a11.y; af1[6] = (__bf16)a11.z; af1[7] = (__bf16)a11.w;
#pragma unroll
        for (int t = 0; t < 4; ++t) {
            bf16x8 bf_ = *(const bf16x8*)(Wtf + ((size_t)(k0c * 4 + t) * 64 + lane) * 8);
            acc[0][t] = __builtin_amdgcn_mfma_f32_16x16x32_bf16(af0, bf_, acc[0][t], 0, 0, 0);
            acc[1][t] = __builtin_amdgcn_mfma_f32_16x16x32_bf16(af1, bf_, acc[1][t], 0, 0, 0);
        }
    }
#pragma unroll
    for (int rr = 0; rr < 2; ++rr)
#pragma unroll
    for (int r = 0; r < 4; ++r) {
        long row = rbase + rr * 16 + lq * 4 + r;
        if (row < nrows) {
            float dv = dinv[row];
#pragma unroll
            for (int t = 0; t < 4; ++t)
                H[(size_t)row * 64 + t * 16 + l15] = (__bf16)(acc[rr][t][r] * dv);
        }
    }
}

// ---------------------------------------------------------------- GEMM2: 64 -> 32 bf16 MFMA, h' = dinv*h
__global__ __launch_bounds__(256) void k_gemm2_mfma(const __bf16* __restrict__ A,
                                                    const __bf16* __restrict__ Wtf2,
                                                    const float* __restrict__ dinv,
                                                    __bf16* __restrict__ H, int nrows) {
    const int wave = threadIdx.x >> 6;
    const int lane = threadIdx.x & 63;
    const int l15  = lane & 15;
    const int lq   = lane >> 4;
    const long rbase = (long)blockIdx.x * 64 + wave * 16;

    long arow = rbase + l15;
    if (arow >= nrows) arow = nrows - 1;

    f32x4 acc[2] = {{0.f,0.f,0.f,0.f},{0.f,0.f,0.f,0.f}};
#pragma unroll
    for (int c = 0; c < 2; ++c) {
        bf16x8 af = *(const bf16x8*)(A + (size_t)arow * 64 + c * 32 + lq * 8);
#pragma unroll
        for (int t = 0; t < 2; ++t) {
            bf16x8 bf_ = *(const bf16x8*)(Wtf2 + ((size_t)(c * 2 + t) * 64 + lane) * 8);
            acc[t] = __builtin_amdgcn_mfma_f32_16x16x32_bf16(af, bf_, acc[t], 0, 0, 0);
        }
    }
#pragma unroll
    for (int r = 0; r < 4; ++r) {
        long row = rbase + lq * 4 + r;
        if (row < nrows) {
            float dv = dinv[row];
#pragma unroll
            for (int t = 0; t < 2; ++t)
                H[(size_t)row * 32 + t * 16 + l15] = (__bf16)(acc[t][r] * dv);
        }
    }
}

// ---------------------------------------------------------------- propagation (CSR gather, bf16 h', 8B/lane)
// h' = dinv*h; out = di*(sum w*h'[src] + h'[nd]) + b ; lane owns 4 channels (8B load)
// EPI 0: relu -> packed bf16    EPI 1: fused lin3 -> h3' = dinv * (relu(o)·W3)
template <int K, int EPI>
__global__ __launch_bounds__(256) void k_prop_bf(const int* __restrict__ offs,
                                                 const int2* __restrict__ csrp,
                                                 const __bf16* __restrict__ hb,
                                                 const float* __restrict__ dinv,
                                                 const float* __restrict__ bias,
                                                 const float* __restrict__ W3,
                                                 void* __restrict__ outv, int n) {
    constexpr int SUB = K / 4;           // lanes per node
    constexpr int NPW = 64 / SUB;        // nodes per wave
    constexpr int NPB = 4 * NPW;         // nodes per block
    const int t    = threadIdx.x;
    const int lane = t & 63;
    const int wave = t >> 6;
    const int chq  = lane & (SUB - 1);   // channel-quad index
    const int sub  = lane / SUB;
    const long nd  = (long)blockIdx.x * NPB + wave * NPW + sub;
    if (nd >= n) return;

    const unsigned short* h = (const unsigned short*)hb;
    const int j0 = offs[nd], j1 = offs[nd + 1];
    float a0 = 0.f, a1 = 0.f, a2 = 0.f, a3 = 0.f;
    int j = j0;
    for (; j + 3 < j1; j += 4) {
        int2 p0 = csrp[j];
        int2 p1 = csrp[j + 1];
        int2 p2 = csrp[j + 2];
        int2 p3 = csrp[j + 3];
        uint2 u0 = *(const uint2*)(h + (size_t)p0.x * K + 4 * chq);
        uint2 u1 = *(const uint2*)(h + (size_t)p1.x * K + 4 * chq);
        uint2 u2 = *(const uint2*)(h + (size_t)p2.x * K + 4 * chq);
        uint2 u3 = *(const uint2*)(h + (size_t)p3.x * K + 4 * chq);
        float w0 = __int_as_float(p0.y), w1 = __int_as_float(p1.y);
        float w2 = __int_as_float(p2.y), w3 = __int_as_float(p3.y);
        a0 = fmaf(w0, blo(u0.x), a0); a1 = fmaf(w0, bhi(u0.x), a1);
        a2 = fmaf(w0, blo(u0.y), a2); a3 = fmaf(w0, bhi(u0.y), a3);
        a0 = fmaf(w1, blo(u1.x), a0); a1 = fmaf(w1, bhi(u1.x), a1);
        a2 = fmaf(w1, blo(u1.y), a2); a3 = fmaf(w1, bhi(u1.y), a3);
        a0 = fmaf(w2, blo(u2.x), a0); a1 = fmaf(w2, bhi(u2.x), a1);
        a2 = fmaf(w2, blo(u2.y), a2); a3 = fmaf(w2, bhi(u2.y), a3);
        a0 = fmaf(w3, blo(u3.x), a0); a1 = fmaf(w3, bhi(u3.x), a1);
        a2 = fmaf(w3, blo(u3.y), a2); a3 = fmaf(w3, bhi(u3.y), a3);
    }
    for (; j < j1; ++j) {
        int2 p0 = csrp[j];
        uint2 u0 = *(const uint2*)(h + (size_t)p0.x * K + 4 * chq);
        float w0 = __int_as_float(p0.y);
        a0 = fmaf(w0, blo(u0.x), a0); a1 = fmaf(w0, bhi(u0.x), a1);
        a2 = fmaf(w0, blo(u0.y), a2); a3 = fmaf(w0, bhi(u0.y), a3);
    }
    const float di = dinv[nd];
    uint2 us = *(const uint2*)(h + (size_t)nd * K + 4 * chq);
    float4 bv = *(const float4*)(bias + 4 * chq);
    float o0 = fmaf(di, a0 + blo(us.x), bv.x);
    float o1 = fmaf(di, a1 + bhi(us.x), bv.y);
    float o2 = fmaf(di, a2 + blo(us.y), bv.z);
    float o3 = fmaf(di, a3 + bhi(us.y), bv.w);
    o0 = fmaxf(o0, 0.f); o1 = fmaxf(o1, 0.f); o2 = fmaxf(o2, 0.f); o3 = fmaxf(o3, 0.f);
    if (EPI == 0) {
        unsigned short s0 = __builtin_bit_cast(unsigned short, (__bf16)o0);
        unsigned short s1 = __builtin_bit_cast(unsigned short, (__bf16)o1);
        unsigned short s2 = __builtin_bit_cast(unsigned short, (__bf16)o2);
        unsigned short s3 = __builtin_bit_cast(unsigned short, (__bf16)o3);
        uint2 pk;
        pk.x = (unsigned)s0 | ((unsigned)s1 << 16);
        pk.y = (unsigned)s2 | ((unsigned)s3 << 16);
        *(uint2*)((unsigned*)outv + (size_t)nd * (K / 2) + 2 * chq) = pk;
    } else {
        float4 wv = *(const float4*)(W3 + 4 * chq);
        float part = o0 * wv.x + o1 * wv.y + o2 * wv.z + o3 * wv.w;
#pragma unroll
        for (int d = SUB / 2; d >= 1; d >>= 1) part += __shfl_xor(part, d, SUB);
        if (chq == 0) ((float*)outv)[nd] = di * part;   // h3' = dinv*h3
    }
}

// output prop: K=1, f32 h3' (pre-scaled by dinv)
__global__ __launch_bounds__(256) void k_prop1(const int* __restrict__ offs,
                                               const int2* __restrict__ csrp,
                                               const float* __restrict__ h,
                                               const float* __restrict__ dinv,
                                               const float* __restrict__ bias,
                                               float* __restrict__ out, int n) {
    long nd = (long)blockIdx.x * BLK + threadIdx.x;
    if (nd >= n) return;
    const int j0 = offs[nd], j1 = offs[nd + 1];
    float acc = 0.f;
    int j = j0;
    for (; j + 3 < j1; j += 4) {
        int2 p0 = csrp[j];
        int2 p1 = csrp[j + 1];
        int2 p2 = csrp[j + 2];
        int2 p3 = csrp[j + 3];
        acc = fmaf(__int_as_float(p0.y), h[p0.x], acc);
        acc = fmaf(__int_as_float(p1.y), h[p1.x], acc);
        acc = fmaf(__int_as_float(p2.y), h[p2.x], acc);
        acc = fmaf(__int_as_float(p3.y), h[p3.x], acc);
    }
    for (; j < j1; ++j) {
        int2 p0 = csrp[j];
        acc = fmaf(__int_as_float(p0.y), h[p0.x], acc);
    }
    const float di = dinv[nd];
    out[nd] = fmaf(di, acc + h[nd], bias[0]);
}

// ---------------------------------------------------------------- launch
extern "C" void kernel_launch(void* const* d_in, const int* in_sizes, int n_in,
                              void* d_out, int out_size, void* d_ws, size_t ws_size,
                              hipStream_t stream) {
    const float* x  = (const float*)d_in[0];
    const void*  ei = d_in[1];
    const float* ew = (const float*)d_in[2];
    const float* W1 = (const float*)d_in[3];
    const float* b1 = (const float*)d_in[4];
    const float* W2 = (const float*)d_in[5];
    const float* b2 = (const float*)d_in[6];
    const float* W3 = (const float*)d_in[7];
    const float* b3 = (const float*)d_in[8];
    float* out = (float*)d_out;

    const int n = in_sizes[0] / 512;
    const int e = in_sizes[2];
    const int nb = (n + 127) >> 7;

    char* ws = (char*)d_ws;
    size_t off = 0;
    auto alloc = [&](size_t bytes) {
        void* p = ws + off;
        off = (off + bytes + 255) & ~(size_t)255;
        return p;
    };
    int2*   binned   = (int2*)  alloc((size_t)e * 8);   // aliased as hbuf1 after k_build
    __bf16* hbuf1    = (__bf16*)binned;                 // n*64*2 = 12.8MB <= e*8
    int*    bkt_cnt  = (int*)   alloc((size_t)(MAXNB + 1) * 4);
    int*    blkbase  = (int*)   alloc((size_t)NBLKBIN * MAXNB * 4);   // 2 MB
    int*    offs     = (int*)   alloc((size_t)(n + 1) * 4);
    int2*   csrp     = (int2*)  alloc((size_t)e * 8);
    float*  dinv     = (float*) alloc((size_t)n * 4);
    __bf16* pb64     = (__bf16*)alloc((size_t)n * 64 * 2);  // relu'd prop1 out (layer2 in)
    __bf16* hbuf2    = (__bf16*)alloc((size_t)n * 32 * 2);  // gemm2 out (scaled)
    float*  h3       = (float*) alloc((size_t)n * 4);       // fused prop2+lin3 out (scaled)
    __bf16* Wtf      = (__bf16*)alloc((size_t)512 * 64 * 2);
    __bf16* Wtf2     = (__bf16*)alloc((size_t)64 * 32 * 2);
    (void)ws_size; (void)n_in; (void)out_size;

    const int gb_n = (n + BLK - 1) / BLK;

    // ---- prep + CSR build (single-pass scatter; bucket offsets via in-LDS prefix)
    k_prep<<<18, 256, 0, stream>>>(W1, W2, Wtf, Wtf2, bkt_cnt, nb);
    k_binhist<<<NBLKBIN, 256, 0, stream>>>(ei, e, bkt_cnt, blkbase, nb);
    k_binscatter<<<NBLKBIN, 256, 0, stream>>>(ei, ew, e, bkt_cnt, blkbase, binned, nb);
    k_build<<<nb, 256, 0, stream>>>(bkt_cnt, binned, dinv, offs, csrp, n, e, nb);

    // ---- layer 1: 512 -> 64 (bf16 MFMA, h'=dinv*h; hbuf1 aliases binned, dead after build)
    k_gemm1_mfma<<<(n + 127) / 128, 256, 0, stream>>>(x, Wtf, dinv, hbuf1, n);
    k_prop_bf<64, 0><<<(n + 15) / 16, 256, 0, stream>>>(offs, csrp, hbuf1, dinv, b1, nullptr, pb64, n);

    // ---- layer 2: 64 -> 32 (bf16 MFMA, scaled), prop fused with lin3 -> h3'
    k_gemm2_mfma<<<(n + 63) / 64, 256, 0, stream>>>(pb64, Wtf2, dinv, hbuf2, n);
    k_prop_bf<32, 1><<<(n + 31) / 32, 256, 0, stream>>>(offs, csrp, hbuf2, dinv, b2, W3, h3, n);

    // ---- layer 3 propagation -> out
    k_prop1<<<gb_n, BLK, 0, stream>>>(offs, csrp, h3, dinv, b3, out, n);
}